// Round 5
// baseline (151.148 us; speedup 1.0000x reference)
//
#include <hip/hip_runtime.h>
#include <hip/hip_bf16.h>
#include <cstdint>

// Problem constants
#define BATCH 8192
#define IN_F  1024
#define OUT_F 1024
#define G_HRS 1e-6f
#define G_LRS 1e-3f
#define PAR_R 2.0f
#define LEVELS 15.0f   // 2^4 - 1

// workspace layout (bytes)
#define WS_PMIN  0                        // 256 f32 per-block min partials
#define WS_PMAX  1024                     // 256 f32 per-block max partials
#define WS_VEFF  4096                     // 1024 f32
#define WS_VID   8192                     // 1024 f32
#define WS_CORR  16384                    // 32 KB (8192 f32)
#define WS_BT    65536                    // 2 MB bf16 W_effT
#define WS_ABF   (65536 + 2097152)        // 16 MB bf16 x
#define WS_NEED_FULL  ((size_t)WS_ABF + (size_t)BATCH * IN_F * 2)

// ---------- helpers ----------
__device__ __forceinline__ unsigned short f2bf(float f) {
    union { float f; unsigned int i; } v; v.f = f;
    unsigned int u = v.i;
    unsigned int r = (u + 0x7FFFu + ((u >> 16) & 1u)) >> 16;  // RNE
    return (unsigned short)r;
}
__device__ __forceinline__ float quant_g(float wv, float wmin, float inv_range) {
    float t = (wv - wmin) * inv_range;                    // [0,1]
    float step = (G_LRS - G_HRS) / LEVELS;
    return rintf(t * LEVELS) * step + G_HRS;              // rintf = RNE = jnp.round
}

// ---------- K1: per-block min/max partials over weight; block 0 zeros veff/vid ----------
__global__ void kprep(const float* __restrict__ w, float* __restrict__ pmin, float* __restrict__ pmax,
                      float* __restrict__ veff, float* __restrict__ vid) {
    int tid = blockIdx.x * blockDim.x + threadIdx.x;
    float lo = 1e30f, hi = -1e30f;
    const float4* w4 = (const float4*)w;
    const int n4 = (IN_F * OUT_F) / 4;                    // 262144
    for (int i = tid; i < n4; i += 256 * 256) {
        float4 q = w4[i];
        lo = fminf(lo, fminf(fminf(q.x, q.y), fminf(q.z, q.w)));
        hi = fmaxf(hi, fmaxf(fmaxf(q.x, q.y), fmaxf(q.z, q.w)));
    }
#pragma unroll
    for (int m = 1; m < 64; m <<= 1) {
        lo = fminf(lo, __shfl_xor(lo, m, 64));
        hi = fmaxf(hi, __shfl_xor(hi, m, 64));
    }
    __shared__ float slo[4], shi[4];
    int wv = threadIdx.x >> 6, ln = threadIdx.x & 63;
    if (ln == 0) { slo[wv] = lo; shi[wv] = hi; }
    __syncthreads();
    if (threadIdx.x == 0) {
        pmin[blockIdx.x] = fminf(fminf(slo[0], slo[1]), fminf(slo[2], slo[3]));
        pmax[blockIdx.x] = fmaxf(fmaxf(shi[0], shi[1]), fmaxf(shi[2], shi[3]));
    }
    if (blockIdx.x == 0) {                                 // zero accumulators for K2's atomics
        float4 z = make_float4(0.f, 0.f, 0.f, 0.f);
        ((float4*)veff)[threadIdx.x] = z;                  // 256 * 4 = 1024
        ((float4*)vid)[threadIdx.x]  = z;
    }
}

// ---------- K2: build W_effT bf16 + accumulate veff/vid ----------
__global__ void kbuildvec(const float* __restrict__ w, const float* __restrict__ pmin,
                          const float* __restrict__ pmax, unsigned short* __restrict__ bt,
                          float* __restrict__ veff, float* __restrict__ vid) {
    float lo = pmin[threadIdx.x], hi = pmax[threadIdx.x];
#pragma unroll
    for (int m = 1; m < 64; m <<= 1) {
        lo = fminf(lo, __shfl_xor(lo, m, 64));
        hi = fmaxf(hi, __shfl_xor(hi, m, 64));
    }
    __shared__ float slo[4], shi[4];
    int wv = threadIdx.x >> 6, ln = threadIdx.x & 63;
    if (ln == 0) { slo[wv] = lo; shi[wv] = hi; }
    __syncthreads();
    float wmin = fminf(fminf(slo[0], slo[1]), fminf(slo[2], slo[3]));
    float wmax = fmaxf(fmaxf(shi[0], shi[1]), fmaxf(shi[2], shi[3]));

    float inv_range = 1.0f / (wmax - wmin);
    float acoef = (G_LRS - G_HRS) * inv_range;
    float bcoef = G_HRS - acoef * wmin;
    float inva = 1.0f / acoef;

    int k0 = threadIdx.x * 4;
    float se[4] = {0.f, 0.f, 0.f, 0.f}, si[4] = {0.f, 0.f, 0.f, 0.f};
#pragma unroll
    for (int rr = 0; rr < 4; rr++) {
        int n = blockIdx.x * 4 + rr;
        float4 q = *(const float4*)&w[(size_t)n * IN_F + k0];
        float wvv[4] = { q.x, q.y, q.z, q.w };
        unsigned short o[4];
#pragma unroll
        for (int j = 0; j < 4; j++) {
            int k = k0 + j;
            float g = quant_g(wvv[j], wmin, inv_range);
            float r = PAR_R * ((float)(n + 1) + (float)(IN_F - k));
            float ge = 1.0f / (1.0f / g + r);
            o[j] = f2bf((ge - bcoef) * inva);
            se[j] += ge;
            si[j] += g;
        }
        uint2 ov;
        ov.x = (unsigned int)o[0] | ((unsigned int)o[1] << 16);
        ov.y = (unsigned int)o[2] | ((unsigned int)o[3] << 16);
        *(uint2*)&bt[(size_t)n * IN_F + k0] = ov;
    }
#pragma unroll
    for (int j = 0; j < 4; j++) {
        atomicAdd(&veff[k0 + j], se[j]);
        atomicAdd(&vid[k0 + j], si[j]);
    }
}

// ---------- K3: corr[row] = (x.v_eff)/(x.v_id); emit bf16 copy of x ----------
__global__ void kcorr(const float* __restrict__ x, const float* __restrict__ veff,
                      const float* __restrict__ vid, float* __restrict__ corr,
                      unsigned short* __restrict__ abf) {
    int row = blockIdx.x * 4 + (threadIdx.x >> 6);
    int lane = threadIdx.x & 63;
    int k0 = lane * 16;                                    // 64 lanes * 16 = 1024
    const float* xr = x + (size_t)row * IN_F + k0;
    float se = 0.f, si = 0.f;
#pragma unroll
    for (int p = 0; p < 4; p++) {
        float4 q  = *(const float4*)(xr + p * 4);
        float4 ve = *(const float4*)(veff + k0 + p * 4);
        float4 vi = *(const float4*)(vid  + k0 + p * 4);
        se += q.x * ve.x + q.y * ve.y + q.z * ve.z + q.w * ve.w;
        si += q.x * vi.x + q.y * vi.y + q.z * vi.z + q.w * vi.w;
        if (abf) {
            uint2 ov;
            ov.x = (unsigned int)f2bf(q.x) | ((unsigned int)f2bf(q.y) << 16);
            ov.y = (unsigned int)f2bf(q.z) | ((unsigned int)f2bf(q.w) << 16);
            *(uint2*)&abf[(size_t)row * IN_F + k0 + p * 4] = ov;
        }
    }
#pragma unroll
    for (int m = 1; m < 64; m <<= 1) {
        se += __shfl_xor(se, m, 64);
        si += __shfl_xor(si, m, 64);
    }
    if (lane == 0) corr[row] = se / si;
}

// ---------- K4: GEMM out = x @ W_eff + bias*corr (32x32x16 MFMA core) ----------
typedef __attribute__((ext_vector_type(8))) short bf16x8;
typedef __attribute__((ext_vector_type(16))) float f32x16;

#define GLD_LDS16(g, l) \
    __builtin_amdgcn_global_load_lds((const __attribute__((address_space(1))) void*)(g), \
                                     (__attribute__((address_space(3))) void*)(l), 16, 0, 0)

template <bool CONVA>
__global__ __launch_bounds__(256) void kgemm(
    const float* __restrict__ Af32,
    const unsigned short* __restrict__ Abf,
    const unsigned short* __restrict__ Bt,   // W_effT [1024,1024] bf16
    const float* __restrict__ bias,          // [1024] f32
    const float* __restrict__ corr,          // [8192] f32
    float* __restrict__ out)                 // [8192,1024] f32
{
    __shared__ unsigned short As0[128 * 32];
    __shared__ unsigned short As1[128 * 32];
    __shared__ unsigned short Bs0[128 * 32];
    __shared__ unsigned short Bs1[128 * 32];
    const int tid = threadIdx.x;
    // grid = (N-blocks, M-blocks): flat%8 == bn, so with round-robin XCD placement each XCD
    // keeps one fixed B column-block (256 KB) hot in its L2.
    const int bn = blockIdx.x * 128;
    const int bm = blockIdx.y * 128;
    const int wave = tid >> 6, lane = tid & 63;
    const int wmL = (wave >> 1) * 64;
    const int wnL = (wave & 1) * 64;
    const int m32 = lane & 31;               // A/B fragment row (m or n)
    const int khalf = lane >> 5;             // k-half selector: k = khalf*8 + j

    f32x16 acc[2][2] = {};                   // wave tile 64x64 = 2x2 of 32x32

    // staging chunk mapping (unchanged, proven): chunk c -> row c>>2, 8-elem k-piece c&3
    const int c0 = tid, c1 = tid + 256;
    const unsigned short* gB0 = Bt + (size_t)(bn + (c0 >> 2)) * IN_F + ((c0 & 3) << 3);
    const unsigned short* gB1 = Bt + (size_t)(bn + (c1 >> 2)) * IN_F + ((c1 & 3) << 3);
    const unsigned short* gA0 = nullptr; const unsigned short* gA1 = nullptr;
    const float* fA0 = nullptr; const float* fA1 = nullptr;
    if (CONVA) {
        fA0 = Af32 + (size_t)(bm + (c0 >> 2)) * IN_F + ((c0 & 3) << 3);
        fA1 = Af32 + (size_t)(bm + (c1 >> 2)) * IN_F + ((c1 & 3) << 3);
    } else {
        gA0 = Abf + (size_t)(bm + (c0 >> 2)) * IN_F + ((c0 & 3) << 3);
        gA1 = Abf + (size_t)(bm + (c1 >> 2)) * IN_F + ((c1 & 3) << 3);
    }

    for (int kb = 0; kb < IN_F; kb += 64) {
        if (CONVA) {
            float4 p[8];
            p[0] = *(const float4*)(fA0 + kb);      p[1] = *(const float4*)(fA0 + kb + 4);
            p[2] = *(const float4*)(fA1 + kb);      p[3] = *(const float4*)(fA1 + kb + 4);
            p[4] = *(const float4*)(fA0 + kb + 32); p[5] = *(const float4*)(fA0 + kb + 36);
            p[6] = *(const float4*)(fA1 + kb + 32); p[7] = *(const float4*)(fA1 + kb + 36);
            uint4 u[4];
#pragma unroll
            for (int j = 0; j < 4; j++) {
                u[j] = make_uint4(
                    (unsigned int)f2bf(p[2*j].x) | ((unsigned int)f2bf(p[2*j].y) << 16),
                    (unsigned int)f2bf(p[2*j].z) | ((unsigned int)f2bf(p[2*j].w) << 16),
                    (unsigned int)f2bf(p[2*j+1].x) | ((unsigned int)f2bf(p[2*j+1].y) << 16),
                    (unsigned int)f2bf(p[2*j+1].z) | ((unsigned int)f2bf(p[2*j+1].w) << 16));
            }
            __syncthreads();
            *(uint4*)&As0[c0 * 8] = u[0];
            *(uint4*)&As0[c1 * 8] = u[1];
            *(uint4*)&As1[c0 * 8] = u[2];
            *(uint4*)&As1[c1 * 8] = u[3];
            GLD_LDS16(gB0 + kb, &Bs0[c0 * 8]);
            GLD_LDS16(gB1 + kb, &Bs0[c1 * 8]);
            GLD_LDS16(gB0 + kb + 32, &Bs1[c0 * 8]);
            GLD_LDS16(gB1 + kb + 32, &Bs1[c1 * 8]);
        } else {
            __syncthreads();
            GLD_LDS16(gA0 + kb,      &As0[c0 * 8]);
            GLD_LDS16(gA1 + kb,      &As0[c1 * 8]);
            GLD_LDS16(gB0 + kb,      &Bs0[c0 * 8]);
            GLD_LDS16(gB1 + kb,      &Bs0[c1 * 8]);
            GLD_LDS16(gA0 + kb + 32, &As1[c0 * 8]);
            GLD_LDS16(gA1 + kb + 32, &As1[c1 * 8]);
            GLD_LDS16(gB0 + kb + 32, &Bs1[c0 * 8]);
            GLD_LDS16(gB1 + kb + 32, &Bs1[c1 * 8]);
        }
        __syncthreads();

        // A-frag: A[m][k], m = m32 (row in tile), k = ks*16 + khalf*8 + j
        // B-frag: B[n][k], n = m32,               k = ks*16 + khalf*8 + j
        bf16x8 af[2], bfv[2];
#pragma unroll
        for (int buf = 0; buf < 2; buf++) {
            const unsigned short* Asb = buf ? As1 : Bs0 - 0;  // placeholder, fixed below
            const unsigned short* As_ = buf ? As1 : As0;
            const unsigned short* Bs_ = buf ? Bs1 : Bs0;
            (void)Asb;
#pragma unroll
            for (int ks = 0; ks < 2; ks++) {
                int ko = ks * 16 + khalf * 8;
#pragma unroll
                for (int mt = 0; mt < 2; mt++)
                    af[mt] = *(const bf16x8*)&As_[(wmL + mt * 32 + m32) * 32 + ko];
#pragma unroll
                for (int nt = 0; nt < 2; nt++)
                    bfv[nt] = *(const bf16x8*)&Bs_[(wnL + nt * 32 + m32) * 32 + ko];
#pragma unroll
                for (int mt = 0; mt < 2; mt++)
#pragma unroll
                    for (int nt = 0; nt < 2; nt++)
                        acc[mt][nt] = __builtin_amdgcn_mfma_f32_32x32x16_bf16(af[mt], bfv[nt], acc[mt][nt], 0, 0, 0);
            }
        }
    }

    // epilogue: C/D layout (verified m74/m101): col = lane&31, row = (reg&3) + 8*(reg>>2) + 4*(lane>>5)
#pragma unroll
    for (int nt = 0; nt < 2; nt++) {
        int gc = bn + wnL + nt * 32 + m32;
        float bv = bias[gc];
#pragma unroll
        for (int mt = 0; mt < 2; mt++) {
            int rbase = bm + wmL + mt * 32 + 4 * khalf;
#pragma unroll
            for (int reg = 0; reg < 16; reg++) {
                int gr = rbase + (reg & 3) + 8 * (reg >> 2);
                out[(size_t)gr * OUT_F + gc] = acc[mt][nt][reg] + bv * corr[gr];
            }
        }
    }
}

// ---------- launch ----------
extern "C" void kernel_launch(void* const* d_in, const int* in_sizes, int n_in,
                              void* d_out, int out_size, void* d_ws, size_t ws_size,
                              hipStream_t stream) {
    const float* x    = (const float*)d_in[0];   // [8192,1024] f32
    const float* w    = (const float*)d_in[1];   // [1024,1024] f32 (out,in)
    const float* bias = (const float*)d_in[2];   // [1024] f32
    float* out = (float*)d_out;

    char* ws = (char*)d_ws;
    float* pmin        = (float*)(ws + WS_PMIN);
    float* pmax        = (float*)(ws + WS_PMAX);
    float* veff        = (float*)(ws + WS_VEFF);
    float* vid         = (float*)(ws + WS_VID);
    float* corr        = (float*)(ws + WS_CORR);
    unsigned short* bt = (unsigned short*)(ws + WS_BT);
    unsigned short* abf = (unsigned short*)(ws + WS_ABF);

    bool full = ws_size >= WS_NEED_FULL;

    kprep<<<256, 256, 0, stream>>>(w, pmin, pmax, veff, vid);
    kbuildvec<<<OUT_F / 4, 256, 0, stream>>>(w, pmin, pmax, bt, veff, vid);
    kcorr<<<BATCH / 4, 256, 0, stream>>>(x, veff, vid, corr, full ? abf : nullptr);
    if (full)
        kgemm<false><<<dim3(OUT_F / 128, BATCH / 128), 256, 0, stream>>>(x, abf, bt, bias, corr, out);
    else
        kgemm<true><<<dim3(OUT_F / 128, BATCH / 128), 256, 0, stream>>>(x, nullptr, bt, bias, corr, out);
}

// Round 6
// 146.823 us; speedup vs baseline: 1.0295x; 1.0295x over previous
//
#include <hip/hip_runtime.h>
#include <hip/hip_bf16.h>
#include <cstdint>

// Problem constants
#define BATCH 8192
#define IN_F  1024
#define OUT_F 1024
#define G_HRS 1e-6f
#define G_LRS 1e-3f
#define PAR_R 2.0f
#define LEVELS 15.0f   // 2^4 - 1

// workspace layout (bytes)
#define WS_PMIN  0                        // 256 f32 per-block min partials
#define WS_PMAX  1024                     // 256 f32 per-block max partials
#define WS_VEFF  4096                     // 1024 f32
#define WS_VID   8192                     // 1024 f32
#define WS_CORR  16384                    // 32 KB (8192 f32)
#define WS_BT    65536                    // 2 MB bf16 W_effT
#define WS_ABF   (65536 + 2097152)        // 16 MB bf16 x
#define WS_NEED_FULL  ((size_t)WS_ABF + (size_t)BATCH * IN_F * 2)

// ---------- helpers ----------
__device__ __forceinline__ unsigned short f2bf(float f) {
    union { float f; unsigned int i; } v; v.f = f;
    unsigned int u = v.i;
    unsigned int r = (u + 0x7FFFu + ((u >> 16) & 1u)) >> 16;  // RNE
    return (unsigned short)r;
}
__device__ __forceinline__ float quant_g(float wv, float wmin, float inv_range) {
    float t = (wv - wmin) * inv_range;                    // [0,1]
    float step = (G_LRS - G_HRS) / LEVELS;
    return rintf(t * LEVELS) * step + G_HRS;              // rintf = RNE = jnp.round
}

// ---------- K1: per-block min/max partials over weight; block 0 zeros veff/vid ----------
__global__ void kprep(const float* __restrict__ w, float* __restrict__ pmin, float* __restrict__ pmax,
                      float* __restrict__ veff, float* __restrict__ vid) {
    int tid = blockIdx.x * blockDim.x + threadIdx.x;
    float lo = 1e30f, hi = -1e30f;
    const float4* w4 = (const float4*)w;
    const int n4 = (IN_F * OUT_F) / 4;                    // 262144
    for (int i = tid; i < n4; i += 256 * 256) {
        float4 q = w4[i];
        lo = fminf(lo, fminf(fminf(q.x, q.y), fminf(q.z, q.w)));
        hi = fmaxf(hi, fmaxf(fmaxf(q.x, q.y), fmaxf(q.z, q.w)));
    }
#pragma unroll
    for (int m = 1; m < 64; m <<= 1) {
        lo = fminf(lo, __shfl_xor(lo, m, 64));
        hi = fmaxf(hi, __shfl_xor(hi, m, 64));
    }
    __shared__ float slo[4], shi[4];
    int wv = threadIdx.x >> 6, ln = threadIdx.x & 63;
    if (ln == 0) { slo[wv] = lo; shi[wv] = hi; }
    __syncthreads();
    if (threadIdx.x == 0) {
        pmin[blockIdx.x] = fminf(fminf(slo[0], slo[1]), fminf(slo[2], slo[3]));
        pmax[blockIdx.x] = fmaxf(fmaxf(shi[0], shi[1]), fmaxf(shi[2], shi[3]));
    }
    if (blockIdx.x == 0) {                                 // zero accumulators for K2's atomics
        float4 z = make_float4(0.f, 0.f, 0.f, 0.f);
        ((float4*)veff)[threadIdx.x] = z;                  // 256 * 4 = 1024
        ((float4*)vid)[threadIdx.x]  = z;
    }
}

// ---------- K2: build W_effT bf16 + accumulate veff/vid ----------
__global__ void kbuildvec(const float* __restrict__ w, const float* __restrict__ pmin,
                          const float* __restrict__ pmax, unsigned short* __restrict__ bt,
                          float* __restrict__ veff, float* __restrict__ vid) {
    float lo = pmin[threadIdx.x], hi = pmax[threadIdx.x];
#pragma unroll
    for (int m = 1; m < 64; m <<= 1) {
        lo = fminf(lo, __shfl_xor(lo, m, 64));
        hi = fmaxf(hi, __shfl_xor(hi, m, 64));
    }
    __shared__ float slo[4], shi[4];
    int wv = threadIdx.x >> 6, ln = threadIdx.x & 63;
    if (ln == 0) { slo[wv] = lo; shi[wv] = hi; }
    __syncthreads();
    float wmin = fminf(fminf(slo[0], slo[1]), fminf(slo[2], slo[3]));
    float wmax = fmaxf(fmaxf(shi[0], shi[1]), fmaxf(shi[2], shi[3]));

    float inv_range = 1.0f / (wmax - wmin);
    float acoef = (G_LRS - G_HRS) * inv_range;
    float bcoef = G_HRS - acoef * wmin;
    float inva = 1.0f / acoef;

    int k0 = threadIdx.x * 4;
    float se[4] = {0.f, 0.f, 0.f, 0.f}, si[4] = {0.f, 0.f, 0.f, 0.f};
#pragma unroll
    for (int rr = 0; rr < 4; rr++) {
        int n = blockIdx.x * 4 + rr;
        float4 q = *(const float4*)&w[(size_t)n * IN_F + k0];
        float wvv[4] = { q.x, q.y, q.z, q.w };
        unsigned short o[4];
#pragma unroll
        for (int j = 0; j < 4; j++) {
            int k = k0 + j;
            float g = quant_g(wvv[j], wmin, inv_range);
            float r = PAR_R * ((float)(n + 1) + (float)(IN_F - k));
            float ge = 1.0f / (1.0f / g + r);
            o[j] = f2bf((ge - bcoef) * inva);
            se[j] += ge;
            si[j] += g;
        }
        uint2 ov;
        ov.x = (unsigned int)o[0] | ((unsigned int)o[1] << 16);
        ov.y = (unsigned int)o[2] | ((unsigned int)o[3] << 16);
        *(uint2*)&bt[(size_t)n * IN_F + k0] = ov;
    }
#pragma unroll
    for (int j = 0; j < 4; j++) {
        atomicAdd(&veff[k0 + j], se[j]);
        atomicAdd(&vid[k0 + j], si[j]);
    }
}

// ---------- K3: corr[row] = (x.v_eff)/(x.v_id); emit bf16 copy of x ----------
// barrier-free: one wave per row, 4 rows per block
__global__ void kcorr(const float* __restrict__ x, const float* __restrict__ veff,
                      const float* __restrict__ vid, float* __restrict__ corr,
                      unsigned short* __restrict__ abf) {
    int row = blockIdx.x * 4 + (threadIdx.x >> 6);
    int lane = threadIdx.x & 63;
    int k0 = lane * 16;                                    // 64 lanes * 16 = 1024
    const float* xr = x + (size_t)row * IN_F + k0;
    float se = 0.f, si = 0.f;
#pragma unroll
    for (int p = 0; p < 4; p++) {
        float4 q  = *(const float4*)(xr + p * 4);
        float4 ve = *(const float4*)(veff + k0 + p * 4);
        float4 vi = *(const float4*)(vid  + k0 + p * 4);
        se += q.x * ve.x + q.y * ve.y + q.z * ve.z + q.w * ve.w;
        si += q.x * vi.x + q.y * vi.y + q.z * vi.z + q.w * vi.w;
        if (abf) {
            uint2 ov;
            ov.x = (unsigned int)f2bf(q.x) | ((unsigned int)f2bf(q.y) << 16);
            ov.y = (unsigned int)f2bf(q.z) | ((unsigned int)f2bf(q.w) << 16);
            *(uint2*)&abf[(size_t)row * IN_F + k0 + p * 4] = ov;
        }
    }
#pragma unroll
    for (int m = 1; m < 64; m <<= 1) {
        se += __shfl_xor(se, m, 64);
        si += __shfl_xor(si, m, 64);
    }
    if (lane == 0) corr[row] = se / si;
}

// ---------- K4: GEMM out = x @ W_eff + bias*corr (16x16x32, BK=64, XCD-swizzled grid) ----------
typedef __attribute__((ext_vector_type(8))) short bf16x8;
typedef __attribute__((ext_vector_type(4))) float f32x4;

#define GLD_LDS16(g, l) \
    __builtin_amdgcn_global_load_lds((const __attribute__((address_space(1))) void*)(g), \
                                     (__attribute__((address_space(3))) void*)(l), 16, 0, 0)

template <bool CONVA>
__global__ __launch_bounds__(256) void kgemm(
    const float* __restrict__ Af32,
    const unsigned short* __restrict__ Abf,
    const unsigned short* __restrict__ Bt,   // W_effT [1024,1024] bf16
    const float* __restrict__ bias,          // [1024] f32
    const float* __restrict__ corr,          // [8192] f32
    float* __restrict__ out)                 // [8192,1024] f32
{
    __shared__ unsigned short As0[128 * 32];
    __shared__ unsigned short As1[128 * 32];
    __shared__ unsigned short Bs0[128 * 32];
    __shared__ unsigned short Bs1[128 * 32];
    const int tid = threadIdx.x;
    // XCD-aware swizzle: with round-robin block->XCD placement (xcd = f&7), XCD c owns
    // bm tiles c*8..c*8+7 (A slice = 2 MB) for ALL bn (B = 2 MB) -> both L2-resident per XCD.
    const int f = blockIdx.x;
    const int bm = ((f & 7) * 8 + ((f >> 3) & 7)) * 128;
    const int bn = (f >> 6) * 128;
    const int wave = tid >> 6, lane = tid & 63;
    const int wmL = (wave >> 1) * 64;
    const int wnL = (wave & 1) * 64;
    const int fr = lane & 15;
    const int fk = (lane >> 4) * 8;
    const int quad = lane >> 4;

    f32x4 acc[4][4] = {};

    // chunk c (0..511): row c>>2, 8-elem k-piece c&3; LDS dest = base + lane*16B (wave-uniform rule)
    const int c0 = tid, c1 = tid + 256;
    const unsigned short* gB0 = Bt + (size_t)(bn + (c0 >> 2)) * IN_F + ((c0 & 3) << 3);
    const unsigned short* gB1 = Bt + (size_t)(bn + (c1 >> 2)) * IN_F + ((c1 & 3) << 3);
    const unsigned short* gA0 = nullptr; const unsigned short* gA1 = nullptr;
    const float* fA0 = nullptr; const float* fA1 = nullptr;
    if (CONVA) {
        fA0 = Af32 + (size_t)(bm + (c0 >> 2)) * IN_F + ((c0 & 3) << 3);
        fA1 = Af32 + (size_t)(bm + (c1 >> 2)) * IN_F + ((c1 & 3) << 3);
    } else {
        gA0 = Abf + (size_t)(bm + (c0 >> 2)) * IN_F + ((c0 & 3) << 3);
        gA1 = Abf + (size_t)(bm + (c1 >> 2)) * IN_F + ((c1 & 3) << 3);
    }

    for (int kb = 0; kb < IN_F; kb += 64) {
        if (CONVA) {
            float4 p[8];
            p[0] = *(const float4*)(fA0 + kb);      p[1] = *(const float4*)(fA0 + kb + 4);
            p[2] = *(const float4*)(fA1 + kb);      p[3] = *(const float4*)(fA1 + kb + 4);
            p[4] = *(const float4*)(fA0 + kb + 32); p[5] = *(const float4*)(fA0 + kb + 36);
            p[6] = *(const float4*)(fA1 + kb + 32); p[7] = *(const float4*)(fA1 + kb + 36);
            uint4 u[4];
#pragma unroll
            for (int j = 0; j < 4; j++) {
                u[j] = make_uint4(
                    (unsigned int)f2bf(p[2*j].x) | ((unsigned int)f2bf(p[2*j].y) << 16),
                    (unsigned int)f2bf(p[2*j].z) | ((unsigned int)f2bf(p[2*j].w) << 16),
                    (unsigned int)f2bf(p[2*j+1].x) | ((unsigned int)f2bf(p[2*j+1].y) << 16),
                    (unsigned int)f2bf(p[2*j+1].z) | ((unsigned int)f2bf(p[2*j+1].w) << 16));
            }
            __syncthreads();
            *(uint4*)&As0[c0 * 8] = u[0];
            *(uint4*)&As0[c1 * 8] = u[1];
            *(uint4*)&As1[c0 * 8] = u[2];
            *(uint4*)&As1[c1 * 8] = u[3];
            GLD_LDS16(gB0 + kb, &Bs0[c0 * 8]);
            GLD_LDS16(gB1 + kb, &Bs0[c1 * 8]);
            GLD_LDS16(gB0 + kb + 32, &Bs1[c0 * 8]);
            GLD_LDS16(gB1 + kb + 32, &Bs1[c1 * 8]);
        } else {
            __syncthreads();
            GLD_LDS16(gA0 + kb,      &As0[c0 * 8]);
            GLD_LDS16(gA1 + kb,      &As0[c1 * 8]);
            GLD_LDS16(gB0 + kb,      &Bs0[c0 * 8]);
            GLD_LDS16(gB1 + kb,      &Bs0[c1 * 8]);
            GLD_LDS16(gA0 + kb + 32, &As1[c0 * 8]);
            GLD_LDS16(gA1 + kb + 32, &As1[c1 * 8]);
            GLD_LDS16(gB0 + kb + 32, &Bs1[c0 * 8]);
            GLD_LDS16(gB1 + kb + 32, &Bs1[c1 * 8]);
        }
        __syncthreads();

        bf16x8 af[4], bfv[4];
#pragma unroll
        for (int mt = 0; mt < 4; mt++)
            af[mt] = *(const bf16x8*)&As0[(wmL + mt * 16 + fr) * 32 + fk];
#pragma unroll
        for (int nt = 0; nt < 4; nt++)
            bfv[nt] = *(const bf16x8*)&Bs0[(wnL + nt * 16 + fr) * 32 + fk];
#pragma unroll
        for (int mt = 0; mt < 4; mt++)
#pragma unroll
            for (int nt = 0; nt < 4; nt++)
                acc[mt][nt] = __builtin_amdgcn_mfma_f32_16x16x32_bf16(af[mt], bfv[nt], acc[mt][nt], 0, 0, 0);
#pragma unroll
        for (int mt = 0; mt < 4; mt++)
            af[mt] = *(const bf16x8*)&As1[(wmL + mt * 16 + fr) * 32 + fk];
#pragma unroll
        for (int nt = 0; nt < 4; nt++)
            bfv[nt] = *(const bf16x8*)&Bs1[(wnL + nt * 16 + fr) * 32 + fk];
#pragma unroll
        for (int mt = 0; mt < 4; mt++)
#pragma unroll
            for (int nt = 0; nt < 4; nt++)
                acc[mt][nt] = __builtin_amdgcn_mfma_f32_16x16x32_bf16(af[mt], bfv[nt], acc[mt][nt], 0, 0, 0);
    }

    // epilogue: out[r][c] = acc + bias[c]*corr[r]  (C/D: col=lane&15, row=quad*4+reg)
#pragma unroll
    for (int nt = 0; nt < 4; nt++) {
        int gc = bn + wnL + nt * 16 + fr;
        float bv = bias[gc];
#pragma unroll
        for (int mt = 0; mt < 4; mt++) {
#pragma unroll
            for (int r = 0; r < 4; r++) {
                int gr = bm + wmL + mt * 16 + quad * 4 + r;
                out[(size_t)gr * OUT_F + gc] = acc[mt][nt][r] + bv * corr[gr];
            }
        }
    }
}

// ---------- launch ----------
extern "C" void kernel_launch(void* const* d_in, const int* in_sizes, int n_in,
                              void* d_out, int out_size, void* d_ws, size_t ws_size,
                              hipStream_t stream) {
    const float* x    = (const float*)d_in[0];   // [8192,1024] f32
    const float* w    = (const float*)d_in[1];   // [1024,1024] f32 (out,in)
    const float* bias = (const float*)d_in[2];   // [1024] f32
    float* out = (float*)d_out;

    char* ws = (char*)d_ws;
    float* pmin        = (float*)(ws + WS_PMIN);
    float* pmax        = (float*)(ws + WS_PMAX);
    float* veff        = (float*)(ws + WS_VEFF);
    float* vid         = (float*)(ws + WS_VID);
    float* corr        = (float*)(ws + WS_CORR);
    unsigned short* bt = (unsigned short*)(ws + WS_BT);
    unsigned short* abf = (unsigned short*)(ws + WS_ABF);

    bool full = ws_size >= WS_NEED_FULL;

    kprep<<<256, 256, 0, stream>>>(w, pmin, pmax, veff, vid);
    kbuildvec<<<OUT_F / 4, 256, 0, stream>>>(w, pmin, pmax, bt, veff, vid);
    kcorr<<<BATCH / 4, 256, 0, stream>>>(x, veff, vid, corr, full ? abf : nullptr);
    if (full)
        kgemm<false><<<512, 256, 0, stream>>>(x, abf, bt, bias, corr, out);
    else
        kgemm<true><<<512, 256, 0, stream>>>(x, nullptr, bt, bias, corr, out);
}